// Round 5
// baseline (271.086 us; speedup 1.0000x reference)
//
#include <hip/hip_runtime.h>

#define B_ 16
#define N_ 1024
#define C_ 768
#define E_ 8
#define H_ 192
#define K_ 2
#define GRID_ 512   // 16 b x 32 tiles; MUST stay <= min co-resident capacity (768)

typedef __bf16 bf16x8 __attribute__((ext_vector_type(8)));
typedef float  f32x4  __attribute__((ext_vector_type(4)));

// ---------------------------------------------------------------------------
// Kernel 1: prep. (a) zero sums + grid-barrier counter (ws is re-poisoned
// 0xAA before every launch). (b) pack fc1_w/fc2_w to bf16 in MFMA-B-fragment
// order: pw1[e][kb=c/32][n=h][c%32], pw2[e][kb=h/32][n=c][h%32].
// (c) transpose gate_w to gwT[d][j][c] (f32).
// ---------------------------------------------------------------------------
__global__ __launch_bounds__(256) void prep_kernel(
    const float* __restrict__ w1, const float* __restrict__ w2,
    const float* __restrict__ gw,
    __bf16* __restrict__ pw1, __bf16* __restrict__ pw2,
    float* __restrict__ gwT, unsigned int* __restrict__ ctrl) {
  if (blockIdx.x == 0 && threadIdx.x < 129) ctrl[threadIdx.x] = 0;  // sums+bar

  int idx = blockIdx.x * 256 + threadIdx.x;            // float4 index
  const int nW4 = (E_ * H_ * C_) / 4;                  // 294912
  if (idx >= nW4) return;
  int flat = idx * 4;
  int e = flat / (H_ * C_);
  int r = flat - e * (H_ * C_);

  {
    float4 a = *(const float4*)(w1 + (size_t)flat);
    int n = r / C_;
    int c = r - n * C_;
    size_t o = ((size_t)(e * 24 + (c >> 5)) * 192 + n) * 32 + (c & 31);
    pw1[o + 0] = (__bf16)a.x; pw1[o + 1] = (__bf16)a.y;
    pw1[o + 2] = (__bf16)a.z; pw1[o + 3] = (__bf16)a.w;
  }
  {
    float4 a = *(const float4*)(w2 + (size_t)flat);
    int n = r / H_;
    int h = r - n * H_;
    size_t o = ((size_t)(e * 6 + (h >> 5)) * 768 + n) * 32 + (h & 31);
    pw2[o + 0] = (__bf16)a.x; pw2[o + 1] = (__bf16)a.y;
    pw2[o + 2] = (__bf16)a.z; pw2[o + 3] = (__bf16)a.w;
  }
  if (idx < (4 * 16 * C_) / 4) {
    int f = idx * 4;
    int d = f / (16 * C_);
    int rr = f - d * (16 * C_);
    int j = rr / C_;
    int c = rr - j * C_;
    const float* src = gw + (size_t)d * C_ * 16 + j;
    float4 v;
    v.x = src[(size_t)(c + 0) * 16]; v.y = src[(size_t)(c + 1) * 16];
    v.z = src[(size_t)(c + 2) * 16]; v.w = src[(size_t)(c + 3) * 16];
    *(float4*)(gwT + (size_t)f) = v;
  }
}

__device__ __forceinline__ bf16x8 cvt8(const float4& a, const float4& b) {
  bf16x8 t;
  t[0] = (__bf16)a.x; t[1] = (__bf16)a.y; t[2] = (__bf16)a.z; t[3] = (__bf16)a.w;
  t[4] = (__bf16)b.x; t[5] = (__bf16)b.y; t[6] = (__bf16)b.z; t[7] = (__bf16)b.w;
  return t;
}

// ---------------------------------------------------------------------------
// Kernel 2: MEGA — gate + grid barrier + top-2 + 2-expert adapter.
// Grid = 512 blocks x 256 thr. b = blockIdx&15 (XCD swizzle: each XCD serves
// 2 b's -> <=4 experts = 2.25MB weights, L2-resident). tile = blockIdx>>4.
// DEADLOCK SAFETY: launch_bounds(256,3) + 50.5KB LDS -> >=3 blocks/CU
// capacity = 768 >= 512 grid -> all blocks co-resident -> spin barrier safe.
// Gate math is bit-identical to the R3-passing version (f32, same order).
// Expert math identical to R4-passing version; rings deepened to 3.
// ---------------------------------------------------------------------------
__global__ __launch_bounds__(256, 3) void mega_kernel(
    const float* __restrict__ x, const int* __restrict__ task_ids,
    const float* __restrict__ eps, const float* __restrict__ gwT,
    const __bf16* __restrict__ pw1, const __bf16* __restrict__ pw2,
    const float* __restrict__ fc1_b, const float* __restrict__ fc2_b,
    float* __restrict__ sums, unsigned int* __restrict__ bar,
    float* __restrict__ out) {
  const int b = blockIdx.x & 15;
  const int tile = blockIdx.x >> 4;
  const int token0 = tile * 32;
  const int tid = threadIdx.x;

  // LDS union: phase A uses xt/sc; phase B uses hs. sumsh is disjoint.
  __shared__ __align__(16) char smem[50464];
  float (*xt)[772] = (float(*)[772])smem;                  // 49408 B
  float (*sc)[16]  = (float(*)[16])(smem + 49408);         // 1024 B
  float* sumsh     = (float*)(smem + 50432);               // 32 B
  __bf16 (*hs)[32][200] = (__bf16(*)[32][200])smem;        // 25600 B (phase B)

  // ======================= Phase A: gating =================================
  {
    const int t = tid & 15;
    const int jg = tid >> 4;
    const int task = task_ids[b];
    const float* wrow = gwT + ((size_t)task * 16 + jg) * C_;
    float part = 0.0f;
#pragma unroll
    for (int pass = 0; pass < 2; ++pass) {
      const int tb = token0 + pass * 16;
      const float* xbase = x + ((size_t)b * N_ + tb) * C_;
      for (int it = 0; it < 12; ++it) {
        int chunk = it * 256 + tid;
        int row = chunk / 192;
        int col4 = chunk - row * 192;
        *(float4*)&xt[row][col4 * 4] =
            *(const float4*)(xbase + (size_t)row * C_ + col4 * 4);
      }
      __syncthreads();
      float acc = 0.0f;
#pragma unroll 4
      for (int c = 0; c < C_; c += 4) {
        float4 xv = *(const float4*)&xt[t][c];
        float4 wv = *(const float4*)(wrow + c);
        acc += xv.x * wv.x + xv.y * wv.y + xv.z * wv.z + xv.w * wv.w;
      }
      sc[t][jg] = acc;
      __syncthreads();
      if (jg < 8) {
        float clean = sc[t][jg];
        float raw = sc[t][jg + 8];
        float sp = (raw > 20.0f) ? raw : log1pf(expf(raw));
        part += clean + eps[((size_t)b * N_ + tb + t) * E_ + jg] * (sp + 0.01f);
      }
      __syncthreads();
    }
    if (jg < 8) sc[t][jg] = part;
    __syncthreads();
    if (tid < 8) {
      float s = 0.0f;
#pragma unroll
      for (int tt = 0; tt < 16; ++tt) s += sc[tt][tid];
      atomicAdd(&sums[b * E_ + tid], s);
    }
    __syncthreads();
  }

  // ======================= grid-wide barrier ===============================
  if (tid == 0) {
    __threadfence();                       // release our sums atomics
    atomicAdd(bar, 1u);
    while (__hip_atomic_load(bar, __ATOMIC_ACQUIRE,
                             __HIP_MEMORY_SCOPE_AGENT) < (unsigned)GRID_)
      __builtin_amdgcn_s_sleep(8);
  }
  __syncthreads();
  if (tid < 8)
    sumsh[tid] = __hip_atomic_load(&sums[b * E_ + tid], __ATOMIC_RELAXED,
                                   __HIP_MEMORY_SCOPE_AGENT);
  __syncthreads();

  // ======================= top-2 (all threads, same result) ===============
  int e_idx[2]; float gate_v[2];
  {
    float best = -INFINITY, best2 = -INFINITY;
    int i1 = 0, i2 = 0;
#pragma unroll
    for (int e = 0; e < E_; ++e) {
      float v = sumsh[e];
      if (v > best) { best2 = best; i2 = i1; best = v; i1 = e; }
      else if (v > best2) { best2 = v; i2 = e; }
    }
    float d = best - best2;
    float st = d / (d + 1e-6f);
    float et = expf(st);
    e_idx[0] = i1; gate_v[0] = et / (et + 1.0f);
    e_idx[1] = i2; gate_v[1] = 1.0f / (et + 1.0f);
  }

  // ======================= Phase B: experts ================================
  const int wave = tid >> 6;
  const int lane = tid & 63;
  const int ln = lane & 15;
  const int q8 = (lane >> 4) * 8;
  const int q4 = (lane >> 4) * 4;

  const float* xrow0 = x + ((size_t)b * N_ + token0 + ln) * C_;
  const float* xrow1 = xrow0 + 16 * C_;

  // ---- GEMM1 for both experts -> hs[0], hs[1]. Ring-3 (prefetch dist 2).
#pragma unroll
  for (int kx = 0; kx < 2; ++kx) {
    const int e = e_idx[kx];
    const float g = gate_v[kx];
    const __bf16* w1l = pw1 + (size_t)e * (24 * 192 * 32)
                            + (size_t)(wave * 48 + ln) * 32 + q8;
    bf16x8 bq[3][3];
    float4 af[3][2][2];
#pragma unroll
    for (int pk = 0; pk < 2; ++pk) {
      const __bf16* nx = w1l + (size_t)pk * 6144;
#pragma unroll
      for (int j = 0; j < 3; ++j) bq[pk][j] = *(const bf16x8*)(nx + j * 512);
      int ko = pk * 32 + q8;
      af[pk][0][0] = *(const float4*)(xrow0 + ko);
      af[pk][0][1] = *(const float4*)(xrow0 + ko + 4);
      af[pk][1][0] = *(const float4*)(xrow1 + ko);
      af[pk][1][1] = *(const float4*)(xrow1 + ko + 4);
    }
    f32x4 c1[2][3] = {};
#pragma unroll
    for (int kb = 0; kb < 24; ++kb) {
      const int p = kb % 3;
      if (kb < 22) {
        const int sl = (kb + 2) % 3;
        const __bf16* nx = w1l + (size_t)(kb + 2) * 6144;
#pragma unroll
        for (int j = 0; j < 3; ++j) bq[sl][j] = *(const bf16x8*)(nx + j * 512);
        int ko = (kb + 2) * 32 + q8;
        af[sl][0][0] = *(const float4*)(xrow0 + ko);
        af[sl][0][1] = *(const float4*)(xrow0 + ko + 4);
        af[sl][1][0] = *(const float4*)(xrow1 + ko);
        af[sl][1][1] = *(const float4*)(xrow1 + ko + 4);
      }
      bf16x8 a0 = cvt8(af[p][0][0], af[p][0][1]);
      bf16x8 a1 = cvt8(af[p][1][0], af[p][1][1]);
#pragma unroll
      for (int j = 0; j < 3; ++j) {
        c1[0][j] = __builtin_amdgcn_mfma_f32_16x16x32_bf16(a0, bq[p][j], c1[0][j], 0, 0, 0);
        c1[1][j] = __builtin_amdgcn_mfma_f32_16x16x32_bf16(a1, bq[p][j], c1[1][j], 0, 0, 0);
      }
    }
    // bias + exact gelu + gate scale -> hs[kx]
#pragma unroll
    for (int j = 0; j < 3; ++j) {
      int col = wave * 48 + j * 16 + ln;
      float b1 = fc1_b[e * H_ + col];
#pragma unroll
      for (int m = 0; m < 2; ++m) {
#pragma unroll
        for (int r = 0; r < 4; ++r) {
          int row = m * 16 + q4 + r;
          float v = c1[m][j][r] + b1;
          float gl = 0.5f * v * (1.0f + erff(v * 0.70710678118f));
          hs[kx][row][col] = (__bf16)(g * gl);
        }
      }
    }
  }
  __syncthreads();

  // ---- GEMM2 in two 96-col passes + epilogue. B ring-3, A ring-2 from LDS.
  const float* xr = x + ((size_t)b * N_ + token0) * C_;
  float* outr = out + ((size_t)b * N_ + token0) * C_;

#pragma unroll
  for (int half = 0; half < 2; ++half) {
    const int colbase = wave * 192 + half * 96;
    f32x4 c2[2][6] = {};
#pragma unroll
    for (int kx = 0; kx < 2; ++kx) {
      const int e = e_idx[kx];
      const __bf16(*hse)[200] = hs[kx];
      const __bf16* w2l = pw2 + (size_t)e * (6 * 768 * 32)
                              + (size_t)(colbase + ln) * 32 + q8;
      bf16x8 bh[3][3], av[2][2];
#pragma unroll
      for (int s = 0; s < 2; ++s) {     // preload steps 0,1 (kb=0)
#pragma unroll
        for (int j = 0; j < 3; ++j)
          bh[s][j] = *(const bf16x8*)(w2l + ((s & 1) * 3 + j) * 512);
      }
      av[0][0] = *(const bf16x8*)&hse[ln][q8];
      av[0][1] = *(const bf16x8*)&hse[16 + ln][q8];
#pragma unroll
      for (int s = 0; s < 12; ++s) {
        const int kb = s >> 1;
        const int sub = s & 1;
        const int p = s % 3;
        if (s < 10) {
          const int s2 = s + 2;
          const int kb2 = s2 >> 1;
          const int sub2 = s2 & 1;
          const int sl = s2 % 3;
          const __bf16* src = w2l + (size_t)kb2 * 24576;
#pragma unroll
          for (int j = 0; j < 3; ++j)
            bh[sl][j] = *(const bf16x8*)(src + (sub2 * 3 + j) * 512);
        }
        if (s < 11 && ((s + 1) & 1) == 0) {   // s odd: load A for kb (s+1)/2
          const int kbn = (s + 1) >> 1;
          av[kbn & 1][0] = *(const bf16x8*)&hse[ln][kbn * 32 + q8];
          av[kbn & 1][1] = *(const bf16x8*)&hse[16 + ln][kbn * 32 + q8];
        }
#pragma unroll
        for (int j = 0; j < 3; ++j) {
          const int jj = sub * 3 + j;
          c2[0][jj] = __builtin_amdgcn_mfma_f32_16x16x32_bf16(av[kb & 1][0], bh[p][j], c2[0][jj], 0, 0, 0);
          c2[1][jj] = __builtin_amdgcn_mfma_f32_16x16x32_bf16(av[kb & 1][1], bh[p][j], c2[1][jj], 0, 0, 0);
        }
      }
    }
    // epilogue for this half: out = x + y + gate-weighted fc2_b
#pragma unroll
    for (int j = 0; j < 6; ++j) {
      int col = colbase + j * 16 + ln;
      float b2t = gate_v[0] * fc2_b[e_idx[0] * C_ + col] +
                  gate_v[1] * fc2_b[e_idx[1] * C_ + col];
#pragma unroll
      for (int m = 0; m < 2; ++m) {
#pragma unroll
        for (int r = 0; r < 4; ++r) {
          int row = m * 16 + q4 + r;
          size_t off = (size_t)row * C_ + col;
          outr[off] = xr[off] + c2[m][j][r] + b2t;
        }
      }
    }
  }
}

// ---------------------------------------------------------------------------
extern "C" void kernel_launch(void* const* d_in, const int* in_sizes, int n_in,
                              void* d_out, int out_size, void* d_ws, size_t ws_size,
                              hipStream_t stream) {
  const float* x      = (const float*)d_in[0];
  const int*   task   = (const int*)d_in[1];
  const float* eps    = (const float*)d_in[2];
  const float* gate_w = (const float*)d_in[3];
  const float* fc1_w  = (const float*)d_in[4];
  const float* fc1_b  = (const float*)d_in[5];
  const float* fc2_w  = (const float*)d_in[6];
  const float* fc2_b  = (const float*)d_in[7];
  float* out = (float*)d_out;

  // workspace: pw1 | pw2 | gwT | sums(128 f32) | bar(1 u32)   (~4.92 MB)
  const size_t nW = (size_t)E_ * H_ * C_;              // 1179648
  __bf16* pw1 = (__bf16*)d_ws;
  __bf16* pw2 = pw1 + nW;
  float* gwT  = (float*)((char*)d_ws + 2 * nW * sizeof(__bf16));
  float* sums = (float*)((char*)gwT + 4 * 16 * C_ * sizeof(float));
  unsigned int* bar = (unsigned int*)(sums + 128);

  prep_kernel<<<(nW / 4 + 255) / 256, 256, 0, stream>>>(
      fc1_w, fc2_w, gate_w, pw1, pw2, gwT, (unsigned int*)sums);
  mega_kernel<<<GRID_, 256, 0, stream>>>(x, task, eps, gwT, pw1, pw2,
                                         fc1_b, fc2_b, sums, bar, out);
}

// Round 6
// 236.957 us; speedup vs baseline: 1.1440x; 1.1440x over previous
//
#include <hip/hip_runtime.h>

#define B_ 16
#define N_ 1024
#define C_ 768
#define E_ 8
#define H_ 192
#define K_ 2
#define GRID_ 512   // 16 b x 32 tiles; <= co-resident capacity (2/CU x 256)

typedef __bf16 bf16x8 __attribute__((ext_vector_type(8)));
typedef float  f32x4  __attribute__((ext_vector_type(4)));

// ---------------------------------------------------------------------------
// Kernel 1: prep. (a) zero sums + grid-barrier counter. (b) pack fc1_w/fc2_w
// to bf16 MFMA-B-fragment order: pw1[e][kb=c/32][n=h][c%32],
// pw2[e][kb=h/32][n=c][h%32]. (c) transpose gate_w to gwT[d][j][c] (f32).
// ---------------------------------------------------------------------------
__global__ __launch_bounds__(256) void prep_kernel(
    const float* __restrict__ w1, const float* __restrict__ w2,
    const float* __restrict__ gw,
    __bf16* __restrict__ pw1, __bf16* __restrict__ pw2,
    float* __restrict__ gwT, unsigned int* __restrict__ ctrl) {
  if (blockIdx.x == 0 && threadIdx.x < 129) ctrl[threadIdx.x] = 0;  // sums+bar

  int idx = blockIdx.x * 256 + threadIdx.x;            // float4 index
  const int nW4 = (E_ * H_ * C_) / 4;                  // 294912
  if (idx >= nW4) return;
  int flat = idx * 4;
  int e = flat / (H_ * C_);
  int r = flat - e * (H_ * C_);

  {
    float4 a = *(const float4*)(w1 + (size_t)flat);
    int n = r / C_;
    int c = r - n * C_;
    size_t o = ((size_t)(e * 24 + (c >> 5)) * 192 + n) * 32 + (c & 31);
    pw1[o + 0] = (__bf16)a.x; pw1[o + 1] = (__bf16)a.y;
    pw1[o + 2] = (__bf16)a.z; pw1[o + 3] = (__bf16)a.w;
  }
  {
    float4 a = *(const float4*)(w2 + (size_t)flat);
    int n = r / H_;
    int h = r - n * H_;
    size_t o = ((size_t)(e * 6 + (h >> 5)) * 768 + n) * 32 + (h & 31);
    pw2[o + 0] = (__bf16)a.x; pw2[o + 1] = (__bf16)a.y;
    pw2[o + 2] = (__bf16)a.z; pw2[o + 3] = (__bf16)a.w;
  }
  if (idx < (4 * 16 * C_) / 4) {
    int f = idx * 4;
    int d = f / (16 * C_);
    int rr = f - d * (16 * C_);
    int j = rr / C_;
    int c = rr - j * C_;
    const float* src = gw + (size_t)d * C_ * 16 + j;
    float4 v;
    v.x = src[(size_t)(c + 0) * 16]; v.y = src[(size_t)(c + 1) * 16];
    v.z = src[(size_t)(c + 2) * 16]; v.w = src[(size_t)(c + 3) * 16];
    *(float4*)(gwT + (size_t)f) = v;
  }
}

// ---------------------------------------------------------------------------
// Kernel 2: MEGA = R5 skeleton (gate phase + grid barrier) with R3's PROVEN
// expert body as phase B (LDS xs staging, ring-2 prefetch, single hs buffer).
// Grid = 512 x 256. b = blockIdx&15 (XCD swizzle), tile = blockIdx>>4.
// DEADLOCK SAFETY: LDS 62464 B -> 2 blocks/CU (R3-measured) -> capacity
// 512 = grid -> all blocks co-resident -> spin barrier safe.
// ---------------------------------------------------------------------------
__global__ __launch_bounds__(256, 2) void mega_kernel(
    const float* __restrict__ x, const int* __restrict__ task_ids,
    const float* __restrict__ eps, const float* __restrict__ gwT,
    const __bf16* __restrict__ pw1, const __bf16* __restrict__ pw2,
    const float* __restrict__ fc1_b, const float* __restrict__ fc2_b,
    float* __restrict__ sums, unsigned int* __restrict__ bar,
    float* __restrict__ out) {
  const int b = blockIdx.x & 15;
  const int tile = blockIdx.x >> 4;
  const int token0 = tile * 32;
  const int tid = threadIdx.x;

  // LDS union: phase A = xt[16][772] + sc[16][16] (50432 B);
  //            phase B = xs[32][776] bf16 + hs[32][200] bf16 (62464 B).
  __shared__ __align__(16) char smem[62464];
  float (*xt)[772]  = (float(*)[772])smem;
  float (*sc)[16]   = (float(*)[16])(smem + 49408);
  __bf16 (*xs)[776] = (__bf16(*)[776])smem;
  __bf16 (*hs)[200] = (__bf16(*)[200])(smem + 49664);

  // ======================= Phase A: gating (R3/R5-proven) ==================
  {
    const int t = tid & 15;
    const int jg = tid >> 4;
    const int task = task_ids[b];
    const float* wrow = gwT + ((size_t)task * 16 + jg) * C_;
    float part = 0.0f;
#pragma unroll
    for (int pass = 0; pass < 2; ++pass) {
      const int tb = token0 + pass * 16;
      const float* xbase = x + ((size_t)b * N_ + tb) * C_;
      for (int it = 0; it < 12; ++it) {
        int chunk = it * 256 + tid;
        int row = chunk / 192;
        int col4 = chunk - row * 192;
        *(float4*)&xt[row][col4 * 4] =
            *(const float4*)(xbase + (size_t)row * C_ + col4 * 4);
      }
      __syncthreads();
      float acc = 0.0f;
#pragma unroll 4
      for (int c = 0; c < C_; c += 4) {
        float4 xv = *(const float4*)&xt[t][c];
        float4 wv = *(const float4*)(wrow + c);
        acc += xv.x * wv.x + xv.y * wv.y + xv.z * wv.z + xv.w * wv.w;
      }
      sc[t][jg] = acc;
      __syncthreads();
      if (jg < 8) {
        float clean = sc[t][jg];
        float raw = sc[t][jg + 8];
        float sp = (raw > 20.0f) ? raw : log1pf(expf(raw));
        part += clean + eps[((size_t)b * N_ + tb + t) * E_ + jg] * (sp + 0.01f);
      }
      __syncthreads();
    }
    if (jg < 8) sc[t][jg] = part;
    __syncthreads();
    if (tid < 8) {
      float s = 0.0f;
#pragma unroll
      for (int tt = 0; tt < 16; ++tt) s += sc[tt][tid];
      atomicAdd(&sums[b * E_ + tid], s);
    }
    __syncthreads();
  }

  // ======================= grid-wide barrier (R5-proven) ===================
  if (tid == 0) {
    __threadfence();
    atomicAdd(bar, 1u);
    while (__hip_atomic_load(bar, __ATOMIC_ACQUIRE,
                             __HIP_MEMORY_SCOPE_AGENT) < (unsigned)GRID_)
      __builtin_amdgcn_s_sleep(8);
  }
  __syncthreads();

  // ======================= top-2 (per-thread, from global, L2-hot) =========
  int e_idx[2]; float gate_v[2];
  {
    float best = -INFINITY, best2 = -INFINITY;
    int i1 = 0, i2 = 0;
#pragma unroll
    for (int e = 0; e < E_; ++e) {
      float v = __hip_atomic_load(&sums[b * E_ + e], __ATOMIC_RELAXED,
                                  __HIP_MEMORY_SCOPE_AGENT);
      if (v > best) { best2 = best; i2 = i1; best = v; i1 = e; }
      else if (v > best2) { best2 = v; i2 = e; }
    }
    float d = best - best2;
    float st = d / (d + 1e-6f);
    float et = expf(st);
    e_idx[0] = i1; gate_v[0] = et / (et + 1.0f);
    e_idx[1] = i2; gate_v[1] = 1.0f / (et + 1.0f);
  }

  // ======================= Phase B: experts (R3-proven body) ===============
  const int wave = tid >> 6;
  const int lane = tid & 63;
  const int ln = lane & 15;
  const int q8 = (lane >> 4) * 8;
  const int q4 = (lane >> 4) * 4;

  // stage x tile f32->bf16 (L2-hot from phase A): 3072 8-float chunks
  const float* xbase = x + ((size_t)b * N_ + token0) * C_;
  for (int it = 0; it < 12; ++it) {
    int chunk = it * 256 + tid;
    int row = chunk / 96;
    int col8 = chunk - row * 96;
    const float* p = xbase + (size_t)row * C_ + col8 * 8;
    float4 v0 = *(const float4*)p;
    float4 v1 = *(const float4*)(p + 4);
    bf16x8 t;
    t[0] = (__bf16)v0.x; t[1] = (__bf16)v0.y; t[2] = (__bf16)v0.z; t[3] = (__bf16)v0.w;
    t[4] = (__bf16)v1.x; t[5] = (__bf16)v1.y; t[6] = (__bf16)v1.z; t[7] = (__bf16)v1.w;
    *(bf16x8*)&xs[row][col8 * 8] = t;
  }
  __syncthreads();

  f32x4 c2[2][12] = {};   // persistent y accumulator (gate folded into h)

  for (int kx = 0; kx < 2; ++kx) {
    const int e = e_idx[kx];
    const float g = gate_v[kx];

    // ---- GEMM1: h = x @ W1^T, waves split H=192 into 4x48, K=768 (24 kb)
    const __bf16* w1l = pw1 + (size_t)e * (24 * 192 * 32)
                            + (size_t)(wave * 48 + ln) * 32 + q8;
    bf16x8 bq[2][3], aq[2][2];
#pragma unroll
    for (int j = 0; j < 3; ++j) bq[0][j] = *(const bf16x8*)(w1l + j * 512);
    aq[0][0] = *(const bf16x8*)&xs[ln][q8];
    aq[0][1] = *(const bf16x8*)&xs[16 + ln][q8];
    f32x4 c1[2][3] = {};
#pragma unroll
    for (int kb = 0; kb < 24; ++kb) {
      int p = kb & 1;
      if (kb < 23) {
        const __bf16* nx = w1l + (size_t)(kb + 1) * 6144;
#pragma unroll
        for (int j = 0; j < 3; ++j) bq[p ^ 1][j] = *(const bf16x8*)(nx + j * 512);
        aq[p ^ 1][0] = *(const bf16x8*)&xs[ln][(kb + 1) * 32 + q8];
        aq[p ^ 1][1] = *(const bf16x8*)&xs[16 + ln][(kb + 1) * 32 + q8];
      }
#pragma unroll
      for (int j = 0; j < 3; ++j) {
        c1[0][j] = __builtin_amdgcn_mfma_f32_16x16x32_bf16(aq[p][0], bq[p][j], c1[0][j], 0, 0, 0);
        c1[1][j] = __builtin_amdgcn_mfma_f32_16x16x32_bf16(aq[p][1], bq[p][j], c1[1][j], 0, 0, 0);
      }
    }
    // bias + exact gelu + gate scale -> hs
#pragma unroll
    for (int j = 0; j < 3; ++j) {
      int col = wave * 48 + j * 16 + ln;
      float b1 = fc1_b[e * H_ + col];
#pragma unroll
      for (int m = 0; m < 2; ++m) {
#pragma unroll
        for (int r = 0; r < 4; ++r) {
          int row = m * 16 + q4 + r;
          float v = c1[m][j][r] + b1;
          float gl = 0.5f * v * (1.0f + erff(v * 0.70710678118f));
          hs[row][col] = (__bf16)(g * gl);
        }
      }
    }
    __syncthreads();

    // ---- GEMM2: y += h @ W2^T, waves split 768 into 4x192, K=192 (6 kb).
    const __bf16* w2l = pw2 + (size_t)e * (6 * 768 * 32)
                            + (size_t)(wave * 192 + ln) * 32 + q8;
    bf16x8 bh[2][6], av[2][2];
#pragma unroll
    for (int j = 0; j < 6; ++j) bh[0][j] = *(const bf16x8*)(w2l + j * 512);
    av[0][0] = *(const bf16x8*)&hs[ln][q8];
    av[0][1] = *(const bf16x8*)&hs[16 + ln][q8];
#pragma unroll
    for (int s = 0; s < 12; ++s) {
      const int kb = s >> 1;
      const int half = s & 1;
      const int p = s & 1;
      if (s < 11) {
        const int s2 = s + 1;
        const int kb2 = s2 >> 1;
        const int half2 = s2 & 1;
        const __bf16* src = w2l + (size_t)kb2 * 24576;
#pragma unroll
        for (int j = 0; j < 6; ++j)
          bh[p ^ 1][j] = *(const bf16x8*)(src + (half2 * 6 + j) * 512);
        if (half2 == 0) {
          av[kb2 & 1][0] = *(const bf16x8*)&hs[ln][kb2 * 32 + q8];
          av[kb2 & 1][1] = *(const bf16x8*)&hs[16 + ln][kb2 * 32 + q8];
        }
      }
#pragma unroll
      for (int j = 0; j < 6; ++j) {
        const int jj = half * 6 + j;
        c2[0][jj] = __builtin_amdgcn_mfma_f32_16x16x32_bf16(av[kb & 1][0], bh[p][j], c2[0][jj], 0, 0, 0);
        c2[1][jj] = __builtin_amdgcn_mfma_f32_16x16x32_bf16(av[kb & 1][1], bh[p][j], c2[1][jj], 0, 0, 0);
      }
    }
    __syncthreads();   // protect hs before next expert overwrites
  }

  // epilogue: out = x + y (+ gate-weighted fc2_b)
  const float* xr = x + ((size_t)b * N_ + token0) * C_;
  float* outr = out + ((size_t)b * N_ + token0) * C_;
#pragma unroll
  for (int j = 0; j < 12; ++j) {
    int col = wave * 192 + j * 16 + ln;
    float b2t = gate_v[0] * fc2_b[e_idx[0] * C_ + col] +
                gate_v[1] * fc2_b[e_idx[1] * C_ + col];
#pragma unroll
    for (int m = 0; m < 2; ++m) {
#pragma unroll
      for (int r = 0; r < 4; ++r) {
        int row = m * 16 + q4 + r;
        size_t off = (size_t)row * C_ + col;
        outr[off] = xr[off] + c2[m][j][r] + b2t;
      }
    }
  }
}

// ---------------------------------------------------------------------------
extern "C" void kernel_launch(void* const* d_in, const int* in_sizes, int n_in,
                              void* d_out, int out_size, void* d_ws, size_t ws_size,
                              hipStream_t stream) {
  const float* x      = (const float*)d_in[0];
  const int*   task   = (const int*)d_in[1];
  const float* eps    = (const float*)d_in[2];
  const float* gate_w = (const float*)d_in[3];
  const float* fc1_w  = (const float*)d_in[4];
  const float* fc1_b  = (const float*)d_in[5];
  const float* fc2_w  = (const float*)d_in[6];
  const float* fc2_b  = (const float*)d_in[7];
  float* out = (float*)d_out;

  // workspace: pw1 | pw2 | gwT | sums(128 f32) | bar(1 u32)   (~4.92 MB)
  const size_t nW = (size_t)E_ * H_ * C_;              // 1179648
  __bf16* pw1 = (__bf16*)d_ws;
  __bf16* pw2 = pw1 + nW;
  float* gwT  = (float*)((char*)d_ws + 2 * nW * sizeof(__bf16));
  float* sums = (float*)((char*)gwT + 4 * 16 * C_ * sizeof(float));
  unsigned int* bar = (unsigned int*)(sums + 128);

  prep_kernel<<<(nW / 4 + 255) / 256, 256, 0, stream>>>(
      fc1_w, fc2_w, gate_w, pw1, pw2, gwT, (unsigned int*)sums);
  mega_kernel<<<GRID_, 256, 0, stream>>>(x, task, eps, gwT, pw1, pw2,
                                         fc1_b, fc2_b, sums, bar, out);
}